// Round 12
// baseline (3529.128 us; speedup 1.0000x reference)
//
#include <hip/hip_runtime.h>
#include <hip/hip_bf16.h>

// Problem constants
#define S_LEN 512
#define BATCH 64
#define DC    200
#define HID   300
#define H4    1200
#define IN_DIM 800
#define G_SPLIT 10          // gate-blocks per recurrence chain (30 h-dims each)

typedef __attribute__((ext_vector_type(8))) short short8b;   // 8 bf16
typedef __attribute__((ext_vector_type(4))) float f32x4;
typedef __attribute__((ext_vector_type(4))) int   i32x4;

__device__ __forceinline__ float sigmoidf_(float x) { return 1.0f / (1.0f + __expf(-x)); }
__device__ __forceinline__ float tanhf_(float x)    { return 2.0f / (1.0f + __expf(-2.0f * x)) - 1.0f; }

// ---------------------------------------------------------------------------
// Weight prep (R7 version). Gate-row permutation: block g owns rows
// [g*128, g*128+128): locals 0..119 = {i,f,g,o} x 30 h-dims, 120..127 pad.
// Whh k-PERMUTED: k-slot g2*32+jj2 <-> h-dim g2*30+jj2 (jj2>=30 zero).
// ---------------------------------------------------------------------------
__global__ void k_prep_w(const float* __restrict__ Whh_l, const float* __restrict__ Whh_r,
                         const float* __restrict__ Wih_l, const float* __restrict__ Wih_r,
                         __hip_bfloat16* __restrict__ Whh_p, __hip_bfloat16* __restrict__ Wih_p) {
    int i = blockIdx.x * 256 + threadIdx.x;        // over 2*1280*320
    if (i >= 2 * 1280 * 320) return;
    int slot = i % 320;
    int R = (i / 320) % 1280;
    int d = i / (320 * 1280);
    int g = R >> 7, local = R & 127;
    float vh = 0.f, vi = 0.f;
    if (local < 120) {
        int q = local / 30, jj = local % 30;
        int n = q * 300 + g * 30 + jj;
        const float* Whh = d ? Whh_r : Whh_l;
        const float* Wih = d ? Wih_r : Wih_l;
        int g2 = slot >> 5, jj2 = slot & 31;
        if (jj2 < 30) vh = Whh[n * 300 + g2 * 30 + jj2];
        if (slot < 300) vi = Wih[n * 300 + slot];
    }
    Whh_p[i] = __float2bfloat16(vh);
    Wih_p[i] = __float2bfloat16(vi);
}

// Zero stamped h-buffer, build permuted bias. Runs every launch (graph replay).
__global__ void k_prep_misc(const float* __restrict__ b_l, const float* __restrict__ b_r,
                            int* __restrict__ hb,           // [2][2][64][100] 16B chunks = 102400 ints
                            float* __restrict__ bias_p) {
    int i = blockIdx.x * 256 + threadIdx.x;
    if (i < 102400) hb[i] = 0;
    if (i < 2 * 1280) {
        int d = i / 1280, R = i % 1280;
        int g = R >> 7, local = R & 127;
        float v = 0.f;
        if (local < 120) { int q = local / 30, jj = local % 30; v = (d ? b_r : b_l)[q * 300 + g * 30 + jj]; }
        bias_p[i] = v;
    }
}

// ---------------------------------------------------------------------------
// K1: fused embedding-gather + linear + tanh, bf16 MFMA, BN=320 (unchanged R7)
// ---------------------------------------------------------------------------
__global__ __launch_bounds__(256) void k_lin(
    const int* __restrict__ cf, const int* __restrict__ bl, const int* __restrict__ br,
    const int* __restrict__ scf, const int* __restrict__ sbl, const int* __restrict__ sbr,
    const float* __restrict__ ce, const float* __restrict__ be,
    const float* __restrict__ sce, const float* __restrict__ sbe,
    const float* __restrict__ W, const float* __restrict__ bias,
    __hip_bfloat16* __restrict__ outL, __hip_bfloat16* __restrict__ outR)
{
    const int z = blockIdx.y;
    const int* dynIdx  = z ? br  : bl;
    const int* statIdx = z ? sbr : sbl;
    __hip_bfloat16* outp = z ? outR : outL;
    const int m0 = blockIdx.x * 64;

    __shared__ __align__(16) __hip_bfloat16 sA[64][40];
    __shared__ __align__(16) __hip_bfloat16 sB[320][40];
    const int t = threadIdx.x, lane = t & 63, wv = t >> 6;

    const int rA = t >> 2, c8A = (t & 3) * 8;
    const int mA = m0 + rA;
    const int idc = cf[mA], idsc = scf[mA], idd = dynIdx[mA], ids = statIdx[mA];

    f32x4 acc[4][5] = {};

    for (int k0 = 0; k0 < IN_DIM; k0 += 32) {
        {
            int k = k0 + c8A;
            int seg = k / 200, kin = k - seg * 200;
            const float* tab = (seg == 0) ? ce : (seg == 1) ? sce : (seg == 2) ? be : sbe;
            int id = (seg == 0) ? idc : (seg == 1) ? idsc : (seg == 2) ? idd : ids;
            const float* tp = tab + (size_t)id * DC + kin;
            f32x4 v0 = *reinterpret_cast<const f32x4*>(tp);
            f32x4 v1 = *reinterpret_cast<const f32x4*>(tp + 4);
            union { short8b v; __hip_bfloat16 h[8]; } u;
#pragma unroll
            for (int q = 0; q < 4; ++q) { u.h[q] = __float2bfloat16(v0[q]); u.h[4 + q] = __float2bfloat16(v1[q]); }
            *reinterpret_cast<short8b*>(&sA[rA][c8A]) = u.v;
        }
#pragma unroll
        for (int j = 0; j < 5; ++j) {
            int i = t + j * 256;
            int n = i >> 2, ch = (i & 3) * 8;
            f32x4 v0 = {0, 0, 0, 0}, v1 = {0, 0, 0, 0};
            if (n < HID) {
                const float* wp = W + (size_t)n * IN_DIM + k0 + ch;
                v0 = *reinterpret_cast<const f32x4*>(wp);
                v1 = *reinterpret_cast<const f32x4*>(wp + 4);
            }
            union { short8b v; __hip_bfloat16 h[8]; } u;
#pragma unroll
            for (int q = 0; q < 4; ++q) { u.h[q] = __float2bfloat16(v0[q]); u.h[4 + q] = __float2bfloat16(v1[q]); }
            *reinterpret_cast<short8b*>(&sB[n][ch]) = u.v;
        }
        __syncthreads();
        const int kl = (lane >> 4) * 8, bb = lane & 15;
#pragma unroll
        for (int mt = 0; mt < 4; ++mt) {
            short8b af = *reinterpret_cast<const short8b*>(&sA[mt * 16 + bb][kl]);
#pragma unroll
            for (int nt = 0; nt < 5; ++nt) {
                short8b bf = *reinterpret_cast<const short8b*>(&sB[(wv * 5 + nt) * 16 + bb][kl]);
                acc[mt][nt] = __builtin_amdgcn_mfma_f32_16x16x32_bf16(af, bf, acc[mt][nt], 0, 0, 0);
            }
        }
        __syncthreads();
    }
    const int bb = lane & 15;
#pragma unroll
    for (int mt = 0; mt < 4; ++mt)
#pragma unroll
        for (int nt = 0; nt < 5; ++nt) {
            int p = (wv * 5 + nt) * 16 + bb;
            float bv = (p < HID) ? bias[p] : 0.f;
#pragma unroll
            for (int r = 0; r < 4; ++r) {
                int m = m0 + mt * 16 + (lane >> 4) * 4 + r;
                float val = (p < HID) ? tanhf_(acc[mt][nt][r] + bv) : 0.f;
                outp[(size_t)m * 320 + p] = __float2bfloat16(val);
            }
        }
}

// ---------------------------------------------------------------------------
// K2: X = A @ Wih_p^T + bias_p, bf16 MFMA 16x16x32 (unchanged R7)
// ---------------------------------------------------------------------------
__global__ __launch_bounds__(256) void k_xgemm(
    const __hip_bfloat16* __restrict__ A,
    const __hip_bfloat16* __restrict__ Wih_p,
    const float* __restrict__ bias_p,
    __hip_bfloat16* __restrict__ Xout)
{
    const int dir = blockIdx.z;
    const int m0 = blockIdx.x * 64;
    const int n0 = blockIdx.y * 128;
    const __hip_bfloat16* Ad = A + (size_t)dir * 32768 * 320;
    const __hip_bfloat16* Wd = Wih_p + (size_t)dir * 1280 * 320;
    const float* bd = bias_p + dir * 1280;
    __hip_bfloat16* Xd = Xout + (size_t)dir * 512 * 64 * 1280;

    __shared__ __align__(16) __hip_bfloat16 sA[64][40];
    __shared__ __align__(16) __hip_bfloat16 sB[128][40];
    const int t = threadIdx.x, lane = t & 63, wv = t >> 6;
    f32x4 acc[4][2] = {};

    for (int k0 = 0; k0 < 320; k0 += 32) {
        {
            int r = t >> 2, kg = (t & 3) * 8;
            *reinterpret_cast<short8b*>(&sA[r][kg]) =
                *reinterpret_cast<const short8b*>(Ad + (size_t)(m0 + r) * 320 + k0 + kg);
        }
#pragma unroll
        for (int i = 0; i < 2; ++i) {
            int c = t + i * 256;
            int r = c >> 2, kg = (c & 3) * 8;
            *reinterpret_cast<short8b*>(&sB[r][kg]) =
                *reinterpret_cast<const short8b*>(Wd + (size_t)(n0 + r) * 320 + k0 + kg);
        }
        __syncthreads();
        const int kl = (lane >> 4) * 8;
#pragma unroll
        for (int mt = 0; mt < 4; ++mt) {
            short8b af = *reinterpret_cast<const short8b*>(&sA[mt * 16 + (lane & 15)][kl]);
#pragma unroll
            for (int nt = 0; nt < 2; ++nt) {
                short8b bf = *reinterpret_cast<const short8b*>(&sB[(wv * 2 + nt) * 16 + (lane & 15)][kl]);
                acc[mt][nt] = __builtin_amdgcn_mfma_f32_16x16x32_bf16(af, bf, acc[mt][nt], 0, 0, 0);
            }
        }
        __syncthreads();
    }
#pragma unroll
    for (int mt = 0; mt < 4; ++mt)
#pragma unroll
        for (int nt = 0; nt < 2; ++nt) {
            int p = n0 + (wv * 2 + nt) * 16 + (lane & 15);
            float bv = bd[p];
#pragma unroll
            for (int r = 0; r < 4; ++r) {
                int m = m0 + mt * 16 + (lane >> 4) * 4 + r;
                int b = m >> 9, s = m & 511;
                Xd[(size_t)(s * 64 + b) * 1280 + p] = __float2bfloat16(acc[mt][nt][r] + bv);
            }
        }
}

// ---------------------------------------------------------------------------
// K3: LSTM recurrence — R7 seqlock protocol, TWO same-dir chains interleaved
// per block (A = batch-group 2gp, B = 2gp+1). While chain A's publishes
// propagate through the coherence fabric, the block computes chain B's full
// phase — next A-poll then succeeds in ~1 round. Both chains share the same
// Whh slice (same dir, same g) -> one 80-VGPR fragment set, no extra LDS.
// 40 blocks = 4 pair-sets (dir x gp) x 10 gate-roles. Closed sets; uniform
// phase order; per-chain protocol bit-identical to R7 (liveness unchanged).
// ---------------------------------------------------------------------------
#define PHASE(B0, CST, XA)                                                          \
  {                                                                                 \
    const int par = tau & 1;                                                        \
    const int s = dir ? (S_LEN - 1 - tau) : tau;                                    \
    i32x4 q[7];                                                                     \
    unsigned done = 0;                                                              \
    const i32x4* hbase = hb + ((size_t)(dir * 2 + par) * 64 + (B0)) * 100;          \
    for (;;) {                                                                      \
      _Pragma("unroll")                                                             \
      for (int k = 0; k < 7; ++k) {                                                 \
        int idx = t + k * 256;                                                      \
        if (idx < 1600 && !((done >> k) & 1))                                       \
          asm volatile("global_load_dwordx4 %0, %1, off sc0 sc1"                    \
                       : "=v"(q[k]) : "v"(hbase + idx) : "memory");                 \
      }                                                                             \
      asm volatile("s_waitcnt vmcnt(0)" ::: "memory");                              \
      bool all = true;                                                              \
      _Pragma("unroll")                                                             \
      for (int k = 0; k < 7; ++k) {                                                 \
        int idx = t + k * 256;                                                      \
        if (idx < 1600 && !((done >> k) & 1)) {                                     \
          if (q[k][0] == tau) done |= 1u << k; else all = false;                    \
        }                                                                           \
      }                                                                             \
      if (all) break;                                                               \
      __builtin_amdgcn_s_sleep(1);                                                  \
    }                                                                               \
    __builtin_amdgcn_sched_barrier(0);                                              \
    _Pragma("unroll")                                                               \
    for (int k = 0; k < 7; ++k) {                                                   \
      int idx = t + k * 256;                                                        \
      if (idx < 1600) {                                                             \
        int b = idx / 100, rem = idx - b * 100;                                     \
        int g2 = rem / 10, c = rem - g2 * 10;                                       \
        int chi = (c < 5) ? c : c - 5;                                              \
        unsigned* dst = ((c < 5) ? sHiW : sLoW) + b * 164 + g2 * 16 + chi * 3;      \
        dst[0] = (unsigned)q[k][1];                                                 \
        dst[1] = (unsigned)q[k][2];                                                 \
        dst[2] = (unsigned)q[k][3];                                                 \
      }                                                                             \
    }                                                                               \
    __syncthreads();                                                                \
    f32x4 acc0, acc1;                                                               \
    _Pragma("unroll")                                                               \
    for (int r = 0; r < 4; ++r) {                                                   \
      acc0[r] = __bfloat162float(XA[r]);                                            \
      acc1[r] = __bfloat162float(XA[4 + r]);                                        \
    }                                                                               \
    _Pragma("unroll")                                                               \
    for (int kt = 0; kt < 10; ++kt) {                                               \
      short8b ahi = *reinterpret_cast<const short8b*>(&sHi[bb][kt * 32 + hi4 * 8]); \
      short8b alo = *reinterpret_cast<const short8b*>(&sLo[bb][kt * 32 + hi4 * 8]); \
      acc0 = __builtin_amdgcn_mfma_f32_16x16x32_bf16(ahi, wB0[kt], acc0, 0, 0, 0);  \
      acc1 = __builtin_amdgcn_mfma_f32_16x16x32_bf16(ahi, wB1[kt], acc1, 0, 0, 0);  \
      acc0 = __builtin_amdgcn_mfma_f32_16x16x32_bf16(alo, wB0[kt], acc0, 0, 0, 0);  \
      acc1 = __builtin_amdgcn_mfma_f32_16x16x32_bf16(alo, wB1[kt], acc1, 0, 0, 0);  \
    }                                                                               \
    _Pragma("unroll")                                                               \
    for (int r = 0; r < 4; ++r) {                                                   \
      int m = hi4 * 4 + r;                                                          \
      sG[m][n0 + bb] = acc0[r];                                                     \
      sG[m][n0 + 16 + bb] = acc1[r];                                                \
    }                                                                               \
    __syncthreads();                                                                \
    if (t < 80) {                                                                   \
      int b = t / 5, c5 = t - (b * 5), jj0 = c5 * 6;                                \
      float hv[6];                                                                  \
      unsigned hius[6], lous[6];                                                    \
      _Pragma("unroll")                                                             \
      for (int u = 0; u < 6; ++u) {                                                 \
        int jj = jj0 + u;                                                           \
        float ig = sigmoidf_(sG[b][jj]);                                            \
        float fg = sigmoidf_(sG[b][30 + jj]);                                       \
        float gg = tanhf_(sG[b][60 + jj]);                                          \
        float og = sigmoidf_(sG[b][90 + jj]);                                       \
        float cn = fg * (CST)[u] + ig * gg;                                         \
        (CST)[u] = cn;                                                              \
        float h = og * tanhf_(cn);                                                  \
        hv[u] = h;                                                                  \
        __hip_bfloat16 hb_ = __float2bfloat16(h);                                   \
        float lof = h - __bfloat162float(hb_);                                      \
        __hip_bfloat16 lb_ = __float2bfloat16(lof);                                 \
        union { __hip_bfloat16 x; unsigned short u16; } ch1{hb_}, ch2{lb_};         \
        hius[u] = ch1.u16; lous[u] = ch2.u16;                                       \
      }                                                                             \
      i32x4 dhi, dlo;                                                               \
      dhi[0] = tau + 1; dhi[1] = (int)(hius[0] | (hius[1] << 16));                  \
      dhi[2] = (int)(hius[2] | (hius[3] << 16)); dhi[3] = (int)(hius[4] | (hius[5] << 16)); \
      dlo[0] = tau + 1; dlo[1] = (int)(lous[0] | (lous[1] << 16));                  \
      dlo[2] = (int)(lous[2] | (lous[3] << 16)); dlo[3] = (int)(lous[4] | (lous[5] << 16)); \
      i32x4* pb = hb + ((size_t)(dir * 2 + (par ^ 1)) * 64 + (B0) + b) * 100 + g * 10 + c5; \
      asm volatile("s_waitcnt vmcnt(0)" ::: "memory");                              \
      asm volatile("global_store_dwordx4 %0, %1, off sc0 sc1" :: "v"(pb), "v"(dhi) : "memory");     \
      asm volatile("global_store_dwordx4 %0, %1, off sc0 sc1" :: "v"(pb + 5), "v"(dlo) : "memory"); \
      float* op = out + ((size_t)((B0) + b) * S_LEN + s) * 600 + dir * 300 + g * 30 + jj0;  \
      _Pragma("unroll")                                                             \
      for (int u = 0; u < 6; ++u) op[u] = hv[u];                                    \
    }                                                                               \
    if (tau < S_LEN - 1) {                                                          \
      const int sn = dir ? (s - 1) : (s + 1);                                       \
      const __hip_bfloat16* xp = X + (((size_t)dir * 512 + sn) * 64 + (B0)) * 1280 + g * 128; \
      _Pragma("unroll")                                                             \
      for (int r = 0; r < 4; ++r) {                                                 \
        int m = hi4 * 4 + r;                                                        \
        (XA)[r]     = xp[(size_t)m * 1280 + n0 + bb];                               \
        (XA)[4 + r] = xp[(size_t)m * 1280 + n0 + 16 + bb];                          \
      }                                                                             \
    }                                                                               \
  }

__global__ __launch_bounds__(256) void k_rec(
    const __hip_bfloat16* __restrict__ X,      // [2][512][64][1280]
    const __hip_bfloat16* __restrict__ Whh_p,  // [2][1280][320] (k-permuted)
    i32x4* __restrict__ hb,                    // [2][2][64][100] stamped chunks
    float* __restrict__ out)                   // [64][512][600]
{
    const int bid = blockIdx.x;
    const int set = bid / G_SPLIT;             // 0..3: (dir, gp)
    const int g   = bid % G_SPLIT;
    const int dir = set >> 1;
    const int gp  = set & 1;
    const int b0A = gp * 32;
    const int b0B = gp * 32 + 16;
    const int t = threadIdx.x;
    const int lane = t & 63, wv = t >> 6;

    __shared__ __align__(16) __hip_bfloat16 sHi[16][328];
    __shared__ __align__(16) __hip_bfloat16 sLo[16][328];
    __shared__ float sG[16][132];
    unsigned* sHiW = (unsigned*)sHi;
    unsigned* sLoW = (unsigned*)sLo;

    const int n0 = wv * 32;
    const int bb = lane & 15;
    const int hi4 = lane >> 4;

    // Whh B-fragments -> registers (shared by both chains; 20 x short8b = 80 VGPRs)
    short8b wB0[10], wB1[10];
    {
        const __hip_bfloat16* Wsrc = Whh_p + ((size_t)dir * 1280 + g * 128) * 320;
#pragma unroll
        for (int kt = 0; kt < 10; ++kt) {
            wB0[kt] = *reinterpret_cast<const short8b*>(Wsrc + (size_t)(n0 + bb) * 320 + kt * 32 + hi4 * 8);
            wB1[kt] = *reinterpret_cast<const short8b*>(Wsrc + (size_t)(n0 + 16 + bb) * 320 + kt * 32 + hi4 * 8);
        }
    }
    // prezero LDS h arrays (pad slots jj>=30 of each 32-block stay zero)
    for (int i = t; i < 16 * 164; i += 256) { sHiW[i] = 0; sLoW[i] = 0; }
    __syncthreads();

    float cstA[6] = {}, cstB[6] = {};          // producer cell state (threads 0..79)

    // X prefetch registers for both chains
    __hip_bfloat16 xaA[8], xaB[8];
    {
        const int s0 = dir ? (S_LEN - 1) : 0;
        const __hip_bfloat16* xpA = X + (((size_t)dir * 512 + s0) * 64 + b0A) * 1280 + g * 128;
        const __hip_bfloat16* xpB = X + (((size_t)dir * 512 + s0) * 64 + b0B) * 1280 + g * 128;
#pragma unroll
        for (int r = 0; r < 4; ++r) {
            int m = hi4 * 4 + r;
            xaA[r]     = xpA[(size_t)m * 1280 + n0 + bb];
            xaA[4 + r] = xpA[(size_t)m * 1280 + n0 + 16 + bb];
            xaB[r]     = xpB[(size_t)m * 1280 + n0 + bb];
            xaB[4 + r] = xpB[(size_t)m * 1280 + n0 + 16 + bb];
        }
    }

    for (int tau = 0; tau < S_LEN; ++tau) {
        PHASE(b0A, cstA, xaA);                 // chain A step tau
        PHASE(b0B, cstB, xaB);                 // chain B step tau (hides A's publish latency)
    }
}

// ---------------------------------------------------------------------------
extern "C" void kernel_launch(void* const* d_in, const int* in_sizes, int n_in,
                              void* d_out, int out_size, void* d_ws, size_t ws_size,
                              hipStream_t stream) {
    const int*   cf    = (const int*)d_in[0];
    const int*   bl    = (const int*)d_in[1];
    const int*   br    = (const int*)d_in[2];
    const int*   scf   = (const int*)d_in[3];
    const int*   sbl   = (const int*)d_in[4];
    const int*   sbr   = (const int*)d_in[5];
    const float* ce    = (const float*)d_in[6];
    const float* be    = (const float*)d_in[7];
    const float* sce   = (const float*)d_in[8];
    const float* sbe   = (const float*)d_in[9];
    const float* Wlin  = (const float*)d_in[10];
    const float* blin  = (const float*)d_in[11];
    const float* Wih_l = (const float*)d_in[12];
    const float* Whh_l = (const float*)d_in[13];
    const float* b_l   = (const float*)d_in[14];
    const float* Wih_r = (const float*)d_in[15];
    const float* Whh_r = (const float*)d_in[16];
    const float* b_r   = (const float*)d_in[17];
    float* out = (float*)d_out;

    // Workspace layout (bytes):
    //   A bf16   [2][32768][320]     :  41,943,040
    //   X bf16   [2][512][64][1280]  : 167,772,160  (ends 209,715,200)
    //   Whh_p bf16 [2][1280][320]    :   1,638,400  (ends 211,353,600)
    //   Wih_p bf16 [2][1280][320]    :   1,638,400  (ends 212,992,000)
    //   bias_p f32 [2][1280]         :      10,240  (ends 213,002,240)
    //   hb chunks [2][2][64][100]x16B:     409,600  (ends 213,411,840)
    char* ws = (char*)d_ws;
    __hip_bfloat16* A_b    = (__hip_bfloat16*)(ws);
    __hip_bfloat16* A_l    = A_b;
    __hip_bfloat16* A_r    = A_b + (size_t)32768 * 320;
    __hip_bfloat16* X      = (__hip_bfloat16*)(ws + 41943040);
    __hip_bfloat16* Whh_p  = (__hip_bfloat16*)(ws + 209715200);
    __hip_bfloat16* Wih_p  = (__hip_bfloat16*)(ws + 211353600);
    float*          bias_p = (float*)(ws + 212992000);
    i32x4*          hb     = (i32x4*)(ws + 213002240);

    k_prep_w<<<dim3((2 * 1280 * 320 + 255) / 256), dim3(256), 0, stream>>>(
        Whh_l, Whh_r, Wih_l, Wih_r, Whh_p, Wih_p);
    k_prep_misc<<<dim3(1280), dim3(256), 0, stream>>>(b_l, b_r, (int*)hb, bias_p);
    k_lin<<<dim3(512, 2), dim3(256), 0, stream>>>(cf, bl, br, scf, sbl, sbr,
                                                  ce, be, sce, sbe, Wlin, blin,
                                                  A_l, A_r);
    k_xgemm<<<dim3(512, 10, 2), dim3(256), 0, stream>>>(A_b, Wih_p, bias_p, X);
    k_rec<<<dim3(40), dim3(256), 0, stream>>>(X, Whh_p, hb, out);
}

// Round 13
// 2558.422 us; speedup vs baseline: 1.3794x; 1.3794x over previous
//
#include <hip/hip_runtime.h>
#include <hip/hip_bf16.h>

// Problem constants
#define S_LEN 512
#define BATCH 64
#define DC    200
#define HID   300
#define H4    1200
#define IN_DIM 800
#define G_SPLIT 10          // gate-blocks per recurrence team (30 h-dims each)

typedef __attribute__((ext_vector_type(8))) short short8b;   // 8 bf16
typedef __attribute__((ext_vector_type(4))) float f32x4;
typedef __attribute__((ext_vector_type(4))) int   i32x4;

__device__ __forceinline__ float sigmoidf_(float x) { return 1.0f / (1.0f + __expf(-x)); }
__device__ __forceinline__ float tanhf_(float x)    { return 2.0f / (1.0f + __expf(-2.0f * x)) - 1.0f; }

// ---------------------------------------------------------------------------
// Weight prep (R7). Gate-row permutation: block g owns rows [g*128,+128):
// locals 0..119 = {i,f,g,o} x 30 h-dims, 120..127 pad.
// Whh k-PERMUTED: k-slot g2*32+jj2 <-> h-dim g2*30+jj2 (jj2>=30 zero).
// ---------------------------------------------------------------------------
__global__ void k_prep_w(const float* __restrict__ Whh_l, const float* __restrict__ Whh_r,
                         const float* __restrict__ Wih_l, const float* __restrict__ Wih_r,
                         __hip_bfloat16* __restrict__ Whh_p, __hip_bfloat16* __restrict__ Wih_p) {
    int i = blockIdx.x * 256 + threadIdx.x;        // over 2*1280*320
    if (i >= 2 * 1280 * 320) return;
    int slot = i % 320;
    int R = (i / 320) % 1280;
    int d = i / (320 * 1280);
    int g = R >> 7, local = R & 127;
    float vh = 0.f, vi = 0.f;
    if (local < 120) {
        int q = local / 30, jj = local % 30;
        int n = q * 300 + g * 30 + jj;
        const float* Whh = d ? Whh_r : Whh_l;
        const float* Wih = d ? Wih_r : Wih_l;
        int g2 = slot >> 5, jj2 = slot & 31;
        if (jj2 < 30) vh = Whh[n * 300 + g2 * 30 + jj2];
        if (slot < 300) vi = Wih[n * 300 + slot];
    }
    Whh_p[i] = __float2bfloat16(vh);
    Wih_p[i] = __float2bfloat16(vi);
}

// Zero stamped h-buffer, build permuted bias. Runs every launch (graph replay).
__global__ void k_prep_misc(const float* __restrict__ b_l, const float* __restrict__ b_r,
                            int* __restrict__ hb,           // [2][2][64][100] 16B chunks = 102400 ints
                            float* __restrict__ bias_p) {
    int i = blockIdx.x * 256 + threadIdx.x;
    if (i < 102400) hb[i] = 0;
    if (i < 2 * 1280) {
        int d = i / 1280, R = i % 1280;
        int g = R >> 7, local = R & 127;
        float v = 0.f;
        if (local < 120) { int q = local / 30, jj = local % 30; v = (d ? b_r : b_l)[q * 300 + g * 30 + jj]; }
        bias_p[i] = v;
    }
}

// ---------------------------------------------------------------------------
// K1: fused embedding-gather + linear + tanh, bf16 MFMA, BN=320 (unchanged R7)
// ---------------------------------------------------------------------------
__global__ __launch_bounds__(256) void k_lin(
    const int* __restrict__ cf, const int* __restrict__ bl, const int* __restrict__ br,
    const int* __restrict__ scf, const int* __restrict__ sbl, const int* __restrict__ sbr,
    const float* __restrict__ ce, const float* __restrict__ be,
    const float* __restrict__ sce, const float* __restrict__ sbe,
    const float* __restrict__ W, const float* __restrict__ bias,
    __hip_bfloat16* __restrict__ outL, __hip_bfloat16* __restrict__ outR)
{
    const int z = blockIdx.y;
    const int* dynIdx  = z ? br  : bl;
    const int* statIdx = z ? sbr : sbl;
    __hip_bfloat16* outp = z ? outR : outL;
    const int m0 = blockIdx.x * 64;

    __shared__ __align__(16) __hip_bfloat16 sA[64][40];
    __shared__ __align__(16) __hip_bfloat16 sB[320][40];
    const int t = threadIdx.x, lane = t & 63, wv = t >> 6;

    const int rA = t >> 2, c8A = (t & 3) * 8;
    const int mA = m0 + rA;
    const int idc = cf[mA], idsc = scf[mA], idd = dynIdx[mA], ids = statIdx[mA];

    f32x4 acc[4][5] = {};

    for (int k0 = 0; k0 < IN_DIM; k0 += 32) {
        {
            int k = k0 + c8A;
            int seg = k / 200, kin = k - seg * 200;
            const float* tab = (seg == 0) ? ce : (seg == 1) ? sce : (seg == 2) ? be : sbe;
            int id = (seg == 0) ? idc : (seg == 1) ? idsc : (seg == 2) ? idd : ids;
            const float* tp = tab + (size_t)id * DC + kin;
            f32x4 v0 = *reinterpret_cast<const f32x4*>(tp);
            f32x4 v1 = *reinterpret_cast<const f32x4*>(tp + 4);
            union { short8b v; __hip_bfloat16 h[8]; } u;
#pragma unroll
            for (int q = 0; q < 4; ++q) { u.h[q] = __float2bfloat16(v0[q]); u.h[4 + q] = __float2bfloat16(v1[q]); }
            *reinterpret_cast<short8b*>(&sA[rA][c8A]) = u.v;
        }
#pragma unroll
        for (int j = 0; j < 5; ++j) {
            int i = t + j * 256;
            int n = i >> 2, ch = (i & 3) * 8;
            f32x4 v0 = {0, 0, 0, 0}, v1 = {0, 0, 0, 0};
            if (n < HID) {
                const float* wp = W + (size_t)n * IN_DIM + k0 + ch;
                v0 = *reinterpret_cast<const f32x4*>(wp);
                v1 = *reinterpret_cast<const f32x4*>(wp + 4);
            }
            union { short8b v; __hip_bfloat16 h[8]; } u;
#pragma unroll
            for (int q = 0; q < 4; ++q) { u.h[q] = __float2bfloat16(v0[q]); u.h[4 + q] = __float2bfloat16(v1[q]); }
            *reinterpret_cast<short8b*>(&sB[n][ch]) = u.v;
        }
        __syncthreads();
        const int kl = (lane >> 4) * 8, bb = lane & 15;
#pragma unroll
        for (int mt = 0; mt < 4; ++mt) {
            short8b af = *reinterpret_cast<const short8b*>(&sA[mt * 16 + bb][kl]);
#pragma unroll
            for (int nt = 0; nt < 5; ++nt) {
                short8b bf = *reinterpret_cast<const short8b*>(&sB[(wv * 5 + nt) * 16 + bb][kl]);
                acc[mt][nt] = __builtin_amdgcn_mfma_f32_16x16x32_bf16(af, bf, acc[mt][nt], 0, 0, 0);
            }
        }
        __syncthreads();
    }
    const int bb = lane & 15;
#pragma unroll
    for (int mt = 0; mt < 4; ++mt)
#pragma unroll
        for (int nt = 0; nt < 5; ++nt) {
            int p = (wv * 5 + nt) * 16 + bb;
            float bv = (p < HID) ? bias[p] : 0.f;
#pragma unroll
            for (int r = 0; r < 4; ++r) {
                int m = m0 + mt * 16 + (lane >> 4) * 4 + r;
                float val = (p < HID) ? tanhf_(acc[mt][nt][r] + bv) : 0.f;
                outp[(size_t)m * 320 + p] = __float2bfloat16(val);
            }
        }
}

// ---------------------------------------------------------------------------
// K2: X = A @ Wih_p^T + bias_p, bf16 MFMA 16x16x32 (unchanged R7)
// ---------------------------------------------------------------------------
__global__ __launch_bounds__(256) void k_xgemm(
    const __hip_bfloat16* __restrict__ A,
    const __hip_bfloat16* __restrict__ Wih_p,
    const float* __restrict__ bias_p,
    __hip_bfloat16* __restrict__ Xout)
{
    const int dir = blockIdx.z;
    const int m0 = blockIdx.x * 64;
    const int n0 = blockIdx.y * 128;
    const __hip_bfloat16* Ad = A + (size_t)dir * 32768 * 320;
    const __hip_bfloat16* Wd = Wih_p + (size_t)dir * 1280 * 320;
    const float* bd = bias_p + dir * 1280;
    __hip_bfloat16* Xd = Xout + (size_t)dir * 512 * 64 * 1280;

    __shared__ __align__(16) __hip_bfloat16 sA[64][40];
    __shared__ __align__(16) __hip_bfloat16 sB[128][40];
    const int t = threadIdx.x, lane = t & 63, wv = t >> 6;
    f32x4 acc[4][2] = {};

    for (int k0 = 0; k0 < 320; k0 += 32) {
        {
            int r = t >> 2, kg = (t & 3) * 8;
            *reinterpret_cast<short8b*>(&sA[r][kg]) =
                *reinterpret_cast<const short8b*>(Ad + (size_t)(m0 + r) * 320 + k0 + kg);
        }
#pragma unroll
        for (int i = 0; i < 2; ++i) {
            int c = t + i * 256;
            int r = c >> 2, kg = (c & 3) * 8;
            *reinterpret_cast<short8b*>(&sB[r][kg]) =
                *reinterpret_cast<const short8b*>(Wd + (size_t)(n0 + r) * 320 + k0 + kg);
        }
        __syncthreads();
        const int kl = (lane >> 4) * 8;
#pragma unroll
        for (int mt = 0; mt < 4; ++mt) {
            short8b af = *reinterpret_cast<const short8b*>(&sA[mt * 16 + (lane & 15)][kl]);
#pragma unroll
            for (int nt = 0; nt < 2; ++nt) {
                short8b bf = *reinterpret_cast<const short8b*>(&sB[(wv * 2 + nt) * 16 + (lane & 15)][kl]);
                acc[mt][nt] = __builtin_amdgcn_mfma_f32_16x16x32_bf16(af, bf, acc[mt][nt], 0, 0, 0);
            }
        }
        __syncthreads();
    }
#pragma unroll
    for (int mt = 0; mt < 4; ++mt)
#pragma unroll
        for (int nt = 0; nt < 2; ++nt) {
            int p = n0 + (wv * 2 + nt) * 16 + (lane & 15);
            float bv = bd[p];
#pragma unroll
            for (int r = 0; r < 4; ++r) {
                int m = m0 + mt * 16 + (lane >> 4) * 4 + r;
                int b = m >> 9, s = m & 511;
                Xd[(size_t)(s * 64 + b) * 1280 + p] = __float2bfloat16(acc[mt][nt][r] + bv);
            }
        }
}

// ---------------------------------------------------------------------------
// K3: LSTM recurrence — R7 seqlock protocol with three local reductions:
//  (1) hi/lo chunk PAIRS adjacent in hb: chunk index = (g*5+cc)*2 + {0=hi,1=lo}
//      -> producer's 2 publishes hit one 32B line (single fabric write).
//  (2) self-chunk LDS shortcut: block g never polls its own 160 chunks; the
//      producer writes them straight into sHi/sLo at publish time (positions
//      disjoint from staging; ordered by the staging barrier).
//  (3) retry backoff s_sleep(4): less MALL hammering from 20k polling threads.
// Protocol (scopes/stamps/parity/monotonicity) bit-identical to R7.
// ---------------------------------------------------------------------------
__global__ __launch_bounds__(256) void k_rec(
    const __hip_bfloat16* __restrict__ X,      // [2][512][64][1280]
    const __hip_bfloat16* __restrict__ Whh_p,  // [2][1280][320] (k-permuted)
    i32x4* __restrict__ hb,                    // [2][2][64][100] stamped chunks (paired hi/lo)
    float* __restrict__ out)                   // [64][512][600]
{
    const int bid = blockIdx.x;
    const int dir = bid / (4 * G_SPLIT);
    const int grp = (bid / G_SPLIT) % 4;
    const int g   = bid % G_SPLIT;
    const int t = threadIdx.x;
    const int lane = t & 63, wv = t >> 6;
    const int b0 = grp * 16;

    __shared__ __align__(16) __hip_bfloat16 sHi[16][328];
    __shared__ __align__(16) __hip_bfloat16 sLo[16][328];
    __shared__ float sG[16][132];
    unsigned* sHiW = (unsigned*)sHi;
    unsigned* sLoW = (unsigned*)sLo;

    const int n0 = wv * 32;
    const int bb = lane & 15;
    const int hi4 = lane >> 4;

    // Whh B-fragments -> registers (step-invariant; 20 x short8b = 80 VGPRs)
    short8b wB0[10], wB1[10];
    {
        const __hip_bfloat16* Wsrc = Whh_p + ((size_t)dir * 1280 + g * 128) * 320;
#pragma unroll
        for (int kt = 0; kt < 10; ++kt) {
            wB0[kt] = *reinterpret_cast<const short8b*>(Wsrc + (size_t)(n0 + bb) * 320 + kt * 32 + hi4 * 8);
            wB1[kt] = *reinterpret_cast<const short8b*>(Wsrc + (size_t)(n0 + 16 + bb) * 320 + kt * 32 + hi4 * 8);
        }
    }
    // prezero LDS h arrays (pad slots jj>=30 of each 32-block stay zero; also
    // provides the tau=0 zero-h initial state for own + remote chunks)
    for (int i = t; i < 16 * 164; i += 256) { sHiW[i] = 0; sLoW[i] = 0; }
    __syncthreads();

    // own-chunk mask: chunks this block produces (never polled, never staged)
    unsigned own_mask = 0;
#pragma unroll
    for (int k = 0; k < 7; ++k) {
        int idx = t + k * 256;
        if (idx < 1600) {
            int pair = (idx % 100) >> 1;       // 0..49
            if (pair / 5 == g) own_mask |= 1u << k;
        }
    }

    float cst[6] = {};                       // producer cell state (threads 0..79)

    // X prefetch registers (8 bf16 per thread)
    __hip_bfloat16 xa[8];
    {
        const int s0 = dir ? (S_LEN - 1) : 0;
        const __hip_bfloat16* xp = X + (((size_t)dir * 512 + s0) * 64 + b0) * 1280 + g * 128;
#pragma unroll
        for (int r = 0; r < 4; ++r) {
            int m = hi4 * 4 + r;
            xa[r]     = xp[(size_t)m * 1280 + n0 + bb];
            xa[4 + r] = xp[(size_t)m * 1280 + n0 + 16 + bb];
        }
    }

    for (int tau = 0; tau < S_LEN; ++tau) {
        const int s = dir ? (S_LEN - 1 - tau) : tau;
        const int par = tau & 1;

        // 1) poll-load stamped chunks (own chunks pre-done; backoff on retry)
        i32x4 q[7];
        unsigned done = own_mask;
        const i32x4* hbase = hb + ((size_t)(dir * 2 + par) * 64 + b0) * 100;
        for (;;) {
#pragma unroll
            for (int k = 0; k < 7; ++k) {
                int idx = t + k * 256;
                if (idx < 1600 && !((done >> k) & 1))
                    asm volatile("global_load_dwordx4 %0, %1, off sc0 sc1"
                                 : "=v"(q[k]) : "v"(hbase + idx) : "memory");
            }
            asm volatile("s_waitcnt vmcnt(0)" ::: "memory");
            bool all = true;
#pragma unroll
            for (int k = 0; k < 7; ++k) {
                int idx = t + k * 256;
                if (idx < 1600 && !((done >> k) & 1)) {
                    if (q[k][0] == tau) done |= 1u << k;
                    else all = false;
                }
            }
            if (all) break;
            __builtin_amdgcn_s_sleep(4);
        }
        __builtin_amdgcn_sched_barrier(0);

        // 2) stage remote payloads -> LDS (own chunks already written by
        //    producer at publish time of step tau-1)
#pragma unroll
        for (int k = 0; k < 7; ++k) {
            int idx = t + k * 256;
            if (idx < 1600 && !((own_mask >> k) & 1)) {
                int b = idx / 100, c2 = idx - b * 100;
                int pair = c2 >> 1, buf = c2 & 1;
                int g2 = pair / 5, chi = pair - g2 * 5;
                unsigned* dst = (buf ? sLoW : sHiW) + b * 164 + g2 * 16 + chi * 3;
                dst[0] = (unsigned)q[k][1];
                dst[1] = (unsigned)q[k][2];
                dst[2] = (unsigned)q[k][3];
            }
        }
        __syncthreads();                    // staging complete (orders producer LDS writes too)

        // 3) gates = X + h_hi @ W + h_lo @ W
        f32x4 acc0, acc1;
#pragma unroll
        for (int r = 0; r < 4; ++r) {
            acc0[r] = __bfloat162float(xa[r]);
            acc1[r] = __bfloat162float(xa[4 + r]);
        }
#pragma unroll
        for (int kt = 0; kt < 10; ++kt) {
            short8b ahi = *reinterpret_cast<const short8b*>(&sHi[bb][kt * 32 + hi4 * 8]);
            short8b alo = *reinterpret_cast<const short8b*>(&sLo[bb][kt * 32 + hi4 * 8]);
            acc0 = __builtin_amdgcn_mfma_f32_16x16x32_bf16(ahi, wB0[kt], acc0, 0, 0, 0);
            acc1 = __builtin_amdgcn_mfma_f32_16x16x32_bf16(ahi, wB1[kt], acc1, 0, 0, 0);
            acc0 = __builtin_amdgcn_mfma_f32_16x16x32_bf16(alo, wB0[kt], acc0, 0, 0, 0);
            acc1 = __builtin_amdgcn_mfma_f32_16x16x32_bf16(alo, wB1[kt], acc1, 0, 0, 0);
        }
#pragma unroll
        for (int r = 0; r < 4; ++r) {
            int m = hi4 * 4 + r;
            sG[m][n0 + bb] = acc0[r];
            sG[m][n0 + 16 + bb] = acc1[r];
        }
        __syncthreads();                    // gates visible; all frag reads of sHi/sLo done

        // 4) producer threads (t<80): nonlin on 6 h-dims, cell in regs,
        //    publish paired chunks (one 32B line) + write own chunks to LDS
        //    for the next step + write out.
        if (t < 80) {
            int b = t / 5, cc = t - (b * 5), jj0 = cc * 6;
            float hv[6];
            unsigned hius[6], lous[6];
#pragma unroll
            for (int u = 0; u < 6; ++u) {
                int jj = jj0 + u;
                float ig = sigmoidf_(sG[b][jj]);
                float fg = sigmoidf_(sG[b][30 + jj]);
                float gg = tanhf_(sG[b][60 + jj]);
                float og = sigmoidf_(sG[b][90 + jj]);
                float cn = fg * cst[u] + ig * gg;
                cst[u] = cn;
                float h = og * tanhf_(cn);
                hv[u] = h;
                __hip_bfloat16 hb_ = __float2bfloat16(h);
                float lof = h - __bfloat162float(hb_);
                __hip_bfloat16 lb_ = __float2bfloat16(lof);
                union { __hip_bfloat16 x; unsigned short u16; } ch1{hb_}, ch2{lb_};
                hius[u] = ch1.u16;
                lous[u] = ch2.u16;
            }
            i32x4 dhi, dlo;
            dhi[0] = tau + 1; dhi[1] = (int)(hius[0] | (hius[1] << 16));
            dhi[2] = (int)(hius[2] | (hius[3] << 16)); dhi[3] = (int)(hius[4] | (hius[5] << 16));
            dlo[0] = tau + 1; dlo[1] = (int)(lous[0] | (lous[1] << 16));
            dlo[2] = (int)(lous[2] | (lous[3] << 16)); dlo[3] = (int)(lous[4] | (lous[5] << 16));
            i32x4* pb = hb + ((size_t)(dir * 2 + (par ^ 1)) * 64 + b0 + b) * 100 + (g * 5 + cc) * 2;
            // guard against same-address store reorder with publish from 2 steps ago
            asm volatile("s_waitcnt vmcnt(0)" ::: "memory");
            asm volatile("global_store_dwordx4 %0, %1, off sc0 sc1" :: "v"(pb), "v"(dhi) : "memory");
            asm volatile("global_store_dwordx4 %0, %1, off sc0 sc1" :: "v"(pb + 1), "v"(dlo) : "memory");
            // own chunks -> LDS for next step (positions disjoint from staging;
            // safe: frag reads of this step are done per the gates barrier)
            unsigned* dHi = sHiW + b * 164 + g * 16 + cc * 3;
            unsigned* dLo = sLoW + b * 164 + g * 16 + cc * 3;
            dHi[0] = (unsigned)dhi[1]; dHi[1] = (unsigned)dhi[2]; dHi[2] = (unsigned)dhi[3];
            dLo[0] = (unsigned)dlo[1]; dLo[1] = (unsigned)dlo[2]; dLo[2] = (unsigned)dlo[3];
            float* op = out + ((size_t)(b0 + b) * S_LEN + s) * 600 + dir * 300 + g * 30 + jj0;
#pragma unroll
            for (int u = 0; u < 6; ++u) op[u] = hv[u];
        }

        // 5) X(t+1) prefetch (overlaps teammates' publish transit)
        if (tau < S_LEN - 1) {
            const int sn = dir ? (s - 1) : (s + 1);
            const __hip_bfloat16* xp = X + (((size_t)dir * 512 + sn) * 64 + b0) * 1280 + g * 128;
#pragma unroll
            for (int r = 0; r < 4; ++r) {
                int m = hi4 * 4 + r;
                xa[r]     = xp[(size_t)m * 1280 + n0 + bb];
                xa[4 + r] = xp[(size_t)m * 1280 + n0 + 16 + bb];
            }
        }
        // no end barrier: next step's poll is the synchronization
    }
}

// ---------------------------------------------------------------------------
extern "C" void kernel_launch(void* const* d_in, const int* in_sizes, int n_in,
                              void* d_out, int out_size, void* d_ws, size_t ws_size,
                              hipStream_t stream) {
    const int*   cf    = (const int*)d_in[0];
    const int*   bl    = (const int*)d_in[1];
    const int*   br    = (const int*)d_in[2];
    const int*   scf   = (const int*)d_in[3];
    const int*   sbl   = (const int*)d_in[4];
    const int*   sbr   = (const int*)d_in[5];
    const float* ce    = (const float*)d_in[6];
    const float* be    = (const float*)d_in[7];
    const float* sce   = (const float*)d_in[8];
    const float* sbe   = (const float*)d_in[9];
    const float* Wlin  = (const float*)d_in[10];
    const float* blin  = (const float*)d_in[11];
    const float* Wih_l = (const float*)d_in[12];
    const float* Whh_l = (const float*)d_in[13];
    const float* b_l   = (const float*)d_in[14];
    const float* Wih_r = (const float*)d_in[15];
    const float* Whh_r = (const float*)d_in[16];
    const float* b_r   = (const float*)d_in[17];
    float* out = (float*)d_out;

    // Workspace layout (bytes):
    //   A bf16   [2][32768][320]     :  41,943,040
    //   X bf16   [2][512][64][1280]  : 167,772,160  (ends 209,715,200)
    //   Whh_p bf16 [2][1280][320]    :   1,638,400  (ends 211,353,600)
    //   Wih_p bf16 [2][1280][320]    :   1,638,400  (ends 212,992,000)
    //   bias_p f32 [2][1280]         :      10,240  (ends 213,002,240)
    //   hb chunks [2][2][64][100]x16B:     409,600  (ends 213,411,840)
    char* ws = (char*)d_ws;
    __hip_bfloat16* A_b    = (__hip_bfloat16*)(ws);
    __hip_bfloat16* A_l    = A_b;
    __hip_bfloat16* A_r    = A_b + (size_t)32768 * 320;
    __hip_bfloat16* X      = (__hip_bfloat16*)(ws + 41943040);
    __hip_bfloat16* Whh_p  = (__hip_bfloat16*)(ws + 209715200);
    __hip_bfloat16* Wih_p  = (__hip_bfloat16*)(ws + 211353600);
    float*          bias_p = (float*)(ws + 212992000);
    i32x4*          hb     = (i32x4*)(ws + 213002240);

    k_prep_w<<<dim3((2 * 1280 * 320 + 255) / 256), dim3(256), 0, stream>>>(
        Whh_l, Whh_r, Wih_l, Wih_r, Whh_p, Wih_p);
    k_prep_misc<<<dim3(1280), dim3(256), 0, stream>>>(b_l, b_r, (int*)hb, bias_p);
    k_lin<<<dim3(512, 2), dim3(256), 0, stream>>>(cf, bl, br, scf, sbl, sbr,
                                                  ce, be, sce, sbe, Wlin, blin,
                                                  A_l, A_r);
    k_xgemm<<<dim3(512, 10, 2), dim3(256), 0, stream>>>(A_b, Wih_p, bias_p, X);
    k_rec<<<dim3(80), dim3(256), 0, stream>>>(X, Whh_p, hb, out);
}

// Round 14
// 2287.624 us; speedup vs baseline: 1.5427x; 1.1184x over previous
//
#include <hip/hip_runtime.h>
#include <hip/hip_bf16.h>

// Problem constants
#define S_LEN 512
#define BATCH 64
#define DC    200
#define HID   300
#define H4    1200
#define IN_DIM 800
#define G_SPLIT 10          // gate-blocks per recurrence team (30 h-dims each)

typedef __attribute__((ext_vector_type(8))) short short8b;   // 8 bf16
typedef __attribute__((ext_vector_type(4))) float f32x4;
typedef __attribute__((ext_vector_type(4))) int   i32x4;

__device__ __forceinline__ float sigmoidf_(float x) { return 1.0f / (1.0f + __expf(-x)); }
__device__ __forceinline__ float tanhf_(float x)    { return 2.0f / (1.0f + __expf(-2.0f * x)) - 1.0f; }

// ---------------------------------------------------------------------------
// Weight prep. Gate-row permutation: block g owns rows [g*128, g*128+128):
// locals 0..119 = {i,f,g,o} x 30 h-dims (j = g*30+jj), 120..127 zero pad.
// Whh k-PERMUTED: k-slot = g2*32 + jj2  <->  h-dim g2*30 + jj2 (jj2>=30 zero).
// Wih keeps plain k 0..299 (+20 pad).
// ---------------------------------------------------------------------------
__global__ void k_prep_w(const float* __restrict__ Whh_l, const float* __restrict__ Whh_r,
                         const float* __restrict__ Wih_l, const float* __restrict__ Wih_r,
                         __hip_bfloat16* __restrict__ Whh_p, __hip_bfloat16* __restrict__ Wih_p) {
    int i = blockIdx.x * 256 + threadIdx.x;        // over 2*1280*320
    if (i >= 2 * 1280 * 320) return;
    int slot = i % 320;
    int R = (i / 320) % 1280;
    int d = i / (320 * 1280);
    int g = R >> 7, local = R & 127;
    float vh = 0.f, vi = 0.f;
    if (local < 120) {
        int q = local / 30, jj = local % 30;
        int n = q * 300 + g * 30 + jj;
        const float* Whh = d ? Whh_r : Whh_l;
        const float* Wih = d ? Wih_r : Wih_l;
        int g2 = slot >> 5, jj2 = slot & 31;
        if (jj2 < 30) vh = Whh[n * 300 + g2 * 30 + jj2];
        if (slot < 300) vi = Wih[n * 300 + slot];
    }
    Whh_p[i] = __float2bfloat16(vh);
    Wih_p[i] = __float2bfloat16(vi);
}

// Zero stamped h-buffer, build permuted bias. Runs every launch (graph replay).
__global__ void k_prep_misc(const float* __restrict__ b_l, const float* __restrict__ b_r,
                            int* __restrict__ hb_st,        // [2][2][64][100] i32x4 = 102400 ints
                            float* __restrict__ bias_p) {
    int i = blockIdx.x * 256 + threadIdx.x;
    if (i < 102400) hb_st[i] = 0;
    if (i < 2 * 1280) {
        int d = i / 1280, R = i % 1280;
        int g = R >> 7, local = R & 127;
        float v = 0.f;
        if (local < 120) { int q = local / 30, jj = local % 30; v = (d ? b_r : b_l)[q * 300 + g * 30 + jj]; }
        bias_p[i] = v;
    }
}

// ---------------------------------------------------------------------------
// K1: fused embedding-gather + linear + tanh, bf16 MFMA, BN=320 (full N).
// ---------------------------------------------------------------------------
__global__ __launch_bounds__(256) void k_lin(
    const int* __restrict__ cf, const int* __restrict__ bl, const int* __restrict__ br,
    const int* __restrict__ scf, const int* __restrict__ sbl, const int* __restrict__ sbr,
    const float* __restrict__ ce, const float* __restrict__ be,
    const float* __restrict__ sce, const float* __restrict__ sbe,
    const float* __restrict__ W, const float* __restrict__ bias,
    __hip_bfloat16* __restrict__ outL, __hip_bfloat16* __restrict__ outR)
{
    const int z = blockIdx.y;
    const int* dynIdx  = z ? br  : bl;
    const int* statIdx = z ? sbr : sbl;
    __hip_bfloat16* outp = z ? outR : outL;
    const int m0 = blockIdx.x * 64;

    __shared__ __align__(16) __hip_bfloat16 sA[64][40];
    __shared__ __align__(16) __hip_bfloat16 sB[320][40];
    const int t = threadIdx.x, lane = t & 63, wv = t >> 6;

    const int rA = t >> 2, c8A = (t & 3) * 8;
    const int mA = m0 + rA;
    const int idc = cf[mA], idsc = scf[mA], idd = dynIdx[mA], ids = statIdx[mA];

    f32x4 acc[4][5] = {};

    for (int k0 = 0; k0 < IN_DIM; k0 += 32) {
        {
            int k = k0 + c8A;
            int seg = k / 200, kin = k - seg * 200;
            const float* tab = (seg == 0) ? ce : (seg == 1) ? sce : (seg == 2) ? be : sbe;
            int id = (seg == 0) ? idc : (seg == 1) ? idsc : (seg == 2) ? idd : ids;
            const float* tp = tab + (size_t)id * DC + kin;
            f32x4 v0 = *reinterpret_cast<const f32x4*>(tp);
            f32x4 v1 = *reinterpret_cast<const f32x4*>(tp + 4);
            union { short8b v; __hip_bfloat16 h[8]; } u;
#pragma unroll
            for (int q = 0; q < 4; ++q) { u.h[q] = __float2bfloat16(v0[q]); u.h[4 + q] = __float2bfloat16(v1[q]); }
            *reinterpret_cast<short8b*>(&sA[rA][c8A]) = u.v;
        }
#pragma unroll
        for (int j = 0; j < 5; ++j) {
            int i = t + j * 256;
            int n = i >> 2, ch = (i & 3) * 8;
            f32x4 v0 = {0, 0, 0, 0}, v1 = {0, 0, 0, 0};
            if (n < HID) {
                const float* wp = W + (size_t)n * IN_DIM + k0 + ch;
                v0 = *reinterpret_cast<const f32x4*>(wp);
                v1 = *reinterpret_cast<const f32x4*>(wp + 4);
            }
            union { short8b v; __hip_bfloat16 h[8]; } u;
#pragma unroll
            for (int q = 0; q < 4; ++q) { u.h[q] = __float2bfloat16(v0[q]); u.h[4 + q] = __float2bfloat16(v1[q]); }
            *reinterpret_cast<short8b*>(&sB[n][ch]) = u.v;
        }
        __syncthreads();
        const int kl = (lane >> 4) * 8, bb = lane & 15;
#pragma unroll
        for (int mt = 0; mt < 4; ++mt) {
            short8b af = *reinterpret_cast<const short8b*>(&sA[mt * 16 + bb][kl]);
#pragma unroll
            for (int nt = 0; nt < 5; ++nt) {
                short8b bf = *reinterpret_cast<const short8b*>(&sB[(wv * 5 + nt) * 16 + bb][kl]);
                acc[mt][nt] = __builtin_amdgcn_mfma_f32_16x16x32_bf16(af, bf, acc[mt][nt], 0, 0, 0);
            }
        }
        __syncthreads();
    }
    const int bb = lane & 15;
#pragma unroll
    for (int mt = 0; mt < 4; ++mt)
#pragma unroll
        for (int nt = 0; nt < 5; ++nt) {
            int p = (wv * 5 + nt) * 16 + bb;
            float bv = (p < HID) ? bias[p] : 0.f;
#pragma unroll
            for (int r = 0; r < 4; ++r) {
                int m = m0 + mt * 16 + (lane >> 4) * 4 + r;
                float val = (p < HID) ? tanhf_(acc[mt][nt][r] + bv) : 0.f;
                outp[(size_t)m * 320 + p] = __float2bfloat16(val);
            }
        }
}

// ---------------------------------------------------------------------------
// K2: X = A @ Wih_p^T + bias_p, bf16 MFMA 16x16x32.
// ---------------------------------------------------------------------------
__global__ __launch_bounds__(256) void k_xgemm(
    const __hip_bfloat16* __restrict__ A,
    const __hip_bfloat16* __restrict__ Wih_p,
    const float* __restrict__ bias_p,
    __hip_bfloat16* __restrict__ Xout)
{
    const int dir = blockIdx.z;
    const int m0 = blockIdx.x * 64;
    const int n0 = blockIdx.y * 128;
    const __hip_bfloat16* Ad = A + (size_t)dir * 32768 * 320;
    const __hip_bfloat16* Wd = Wih_p + (size_t)dir * 1280 * 320;
    const float* bd = bias_p + dir * 1280;
    __hip_bfloat16* Xd = Xout + (size_t)dir * 512 * 64 * 1280;

    __shared__ __align__(16) __hip_bfloat16 sA[64][40];
    __shared__ __align__(16) __hip_bfloat16 sB[128][40];
    const int t = threadIdx.x, lane = t & 63, wv = t >> 6;
    f32x4 acc[4][2] = {};

    for (int k0 = 0; k0 < 320; k0 += 32) {
        {
            int r = t >> 2, kg = (t & 3) * 8;
            *reinterpret_cast<short8b*>(&sA[r][kg]) =
                *reinterpret_cast<const short8b*>(Ad + (size_t)(m0 + r) * 320 + k0 + kg);
        }
#pragma unroll
        for (int i = 0; i < 2; ++i) {
            int c = t + i * 256;
            int r = c >> 2, kg = (c & 3) * 8;
            *reinterpret_cast<short8b*>(&sB[r][kg]) =
                *reinterpret_cast<const short8b*>(Wd + (size_t)(n0 + r) * 320 + k0 + kg);
        }
        __syncthreads();
        const int kl = (lane >> 4) * 8;
#pragma unroll
        for (int mt = 0; mt < 4; ++mt) {
            short8b af = *reinterpret_cast<const short8b*>(&sA[mt * 16 + (lane & 15)][kl]);
#pragma unroll
            for (int nt = 0; nt < 2; ++nt) {
                short8b bf = *reinterpret_cast<const short8b*>(&sB[(wv * 2 + nt) * 16 + (lane & 15)][kl]);
                acc[mt][nt] = __builtin_amdgcn_mfma_f32_16x16x32_bf16(af, bf, acc[mt][nt], 0, 0, 0);
            }
        }
        __syncthreads();
    }
#pragma unroll
    for (int mt = 0; mt < 4; ++mt)
#pragma unroll
        for (int nt = 0; nt < 2; ++nt) {
            int p = n0 + (wv * 2 + nt) * 16 + (lane & 15);
            float bv = bd[p];
#pragma unroll
            for (int r = 0; r < 4; ++r) {
                int m = m0 + mt * 16 + (lane >> 4) * 4 + r;
                int b = m >> 9, s = m & 511;
                Xd[(size_t)(s * 64 + b) * 1280 + p] = __float2bfloat16(acc[mt][nt][r] + bv);
            }
        }
}

// ---------------------------------------------------------------------------
// K3: LSTM recurrence — seqlock-stamped h exchange (no tags, no drain legs).
// 80 blocks = 2 dirs x 4 batch-groups(16) x 10 gate-blocks.
// h chunk = 16B [stamp=tau+1 | 6 bf16], one dwordx4 sc0sc1 store (16B atomic).
// Consumer: poll-load its 1600 chunks (7/thread, one vmcnt) until all stamps
// == tau — readiness + data in ONE round trip. Stage payload -> LDS -> MFMA.
// Producer: 80 threads compute 6 h-dims each (cell state in registers),
// pack + store 2 stamped chunks, write out. 2 barriers/step.
// ---------------------------------------------------------------------------
__global__ __launch_bounds__(256) void k_rec(
    const __hip_bfloat16* __restrict__ X,      // [2][512][64][1280]
    const __hip_bfloat16* __restrict__ Whh_p,  // [2][1280][320] (k-permuted)
    i32x4* __restrict__ hb_st,                 // [2][2][64][100] stamped chunks
    float* __restrict__ out)                   // [64][512][600]
{
    const int bid = blockIdx.x;
    const int dir = bid / (4 * G_SPLIT);
    const int grp = (bid / G_SPLIT) % 4;
    const int g   = bid % G_SPLIT;
    const int t = threadIdx.x;
    const int lane = t & 63, wv = t >> 6;
    const int b0 = grp * 16;

    __shared__ __align__(16) __hip_bfloat16 sHi[16][328];   // stride 656B: 2-way max on frag reads
    __shared__ __align__(16) __hip_bfloat16 sLo[16][328];
    __shared__ float sG[16][132];
    unsigned* sHiW = (unsigned*)sHi;
    unsigned* sLoW = (unsigned*)sLo;

    const int n0 = wv * 32;
    const int bb = lane & 15;
    const int hi4 = lane >> 4;

    // Whh B-fragments -> registers (step-invariant; 20 x short8b = 80 VGPRs)
    short8b wB0[10], wB1[10];
    {
        const __hip_bfloat16* Wsrc = Whh_p + ((size_t)dir * 1280 + g * 128) * 320;
#pragma unroll
        for (int kt = 0; kt < 10; ++kt) {
            wB0[kt] = *reinterpret_cast<const short8b*>(Wsrc + (size_t)(n0 + bb) * 320 + kt * 32 + hi4 * 8);
            wB1[kt] = *reinterpret_cast<const short8b*>(Wsrc + (size_t)(n0 + 16 + bb) * 320 + kt * 32 + hi4 * 8);
        }
    }
    // prezero LDS h arrays (pad slots jj>=30 stay zero forever)
    for (int i = t; i < 16 * 164; i += 256) { sHiW[i] = 0; sLoW[i] = 0; }
    __syncthreads();

    float cst[6] = {};                       // producer cell state (threads 0..79)

    // X prefetch registers (8 bf16 per thread)
    __hip_bfloat16 xa[8];
    {
        const int s0 = dir ? (S_LEN - 1) : 0;
        const __hip_bfloat16* xp = X + (((size_t)dir * 512 + s0) * 64 + b0) * 1280 + g * 128;
#pragma unroll
        for (int r = 0; r < 4; ++r) {
            int m = hi4 * 4 + r;
            xa[r]     = xp[(size_t)m * 1280 + n0 + bb];
            xa[4 + r] = xp[(size_t)m * 1280 + n0 + 16 + bb];
        }
    }

    for (int tau = 0; tau < S_LEN; ++tau) {
        const int s = dir ? (S_LEN - 1 - tau) : tau;
        const int par = tau & 1;

        // 1) poll-load stamped chunks: ready when every stamp == tau
        i32x4 ch[7];
        const i32x4* hbase = hb_st + ((size_t)(dir * 2 + par) * 64 + b0) * 100;
        for (;;) {
            bool ok = true;
#pragma unroll
            for (int k = 0; k < 7; ++k) {
                int idx = t + k * 256;
                if (idx < 1600)
                    asm volatile("global_load_dwordx4 %0, %1, off sc0 sc1"
                                 : "=v"(ch[k]) : "v"(hbase + idx) : "memory");
            }
            asm volatile("s_waitcnt vmcnt(0)" ::: "memory");
#pragma unroll
            for (int k = 0; k < 7; ++k) {
                int idx = t + k * 256;
                if (idx < 1600 && ch[k][0] != tau) ok = false;
            }
            if (ok) break;
            __builtin_amdgcn_s_sleep(1);
        }
        __builtin_amdgcn_sched_barrier(0);

        // 2) stage payloads -> LDS (strip stamps)
#pragma unroll
        for (int k = 0; k < 7; ++k) {
            int idx = t + k * 256;
            if (idx < 1600) {
                int b = idx / 100, rem = idx - b * 100;
                int g2 = rem / 10, c = rem - g2 * 10;
                int chi = (c < 5) ? c : c - 5;
                unsigned* dst = ((c < 5) ? sHiW : sLoW) + b * 164 + g2 * 16 + chi * 3;
                dst[0] = (unsigned)ch[k][1];
                dst[1] = (unsigned)ch[k][2];
                dst[2] = (unsigned)ch[k][3];
            }
        }
        __syncthreads();                    // staging complete

        // 3) gates = X + h_hi @ W + h_lo @ W
        f32x4 acc0, acc1;
#pragma unroll
        for (int r = 0; r < 4; ++r) {
            acc0[r] = __bfloat162float(xa[r]);
            acc1[r] = __bfloat162float(xa[4 + r]);
        }
#pragma unroll
        for (int kt = 0; kt < 10; ++kt) {
            short8b ahi = *reinterpret_cast<const short8b*>(&sHi[bb][kt * 32 + hi4 * 8]);
            short8b alo = *reinterpret_cast<const short8b*>(&sLo[bb][kt * 32 + hi4 * 8]);
            acc0 = __builtin_amdgcn_mfma_f32_16x16x32_bf16(ahi, wB0[kt], acc0, 0, 0, 0);
            acc1 = __builtin_amdgcn_mfma_f32_16x16x32_bf16(ahi, wB1[kt], acc1, 0, 0, 0);
            acc0 = __builtin_amdgcn_mfma_f32_16x16x32_bf16(alo, wB0[kt], acc0, 0, 0, 0);
            acc1 = __builtin_amdgcn_mfma_f32_16x16x32_bf16(alo, wB1[kt], acc1, 0, 0, 0);
        }
#pragma unroll
        for (int r = 0; r < 4; ++r) {
            int m = hi4 * 4 + r;
            sG[m][n0 + bb] = acc0[r];
            sG[m][n0 + 16 + bb] = acc1[r];
        }
        __syncthreads();                    // gates visible; frag reads done

        // 4) producer threads (t<80): nonlin on 6 h-dims, cell in regs,
        //    pack stamped chunks, publish, write out.
        if (t < 80) {
            int b = t / 5, c5 = t - (b * 5), jj0 = c5 * 6;
            float hv[6];
            unsigned hius[6], lous[6];
#pragma unroll
            for (int u = 0; u < 6; ++u) {
                int jj = jj0 + u;
                float ig = sigmoidf_(sG[b][jj]);
                float fg = sigmoidf_(sG[b][30 + jj]);
                float gg = tanhf_(sG[b][60 + jj]);
                float og = sigmoidf_(sG[b][90 + jj]);
                float cn = fg * cst[u] + ig * gg;
                cst[u] = cn;
                float h = og * tanhf_(cn);
                hv[u] = h;
                __hip_bfloat16 hb_ = __float2bfloat16(h);
                float lof = h - __bfloat162float(hb_);
                __hip_bfloat16 lb_ = __float2bfloat16(lof);
                union { __hip_bfloat16 x; unsigned short u16; } ch1{hb_}, ch2{lb_};
                hius[u] = ch1.u16;
                lous[u] = ch2.u16;
            }
            i32x4 dhi, dlo;
            dhi[0] = tau + 1; dhi[1] = (int)(hius[0] | (hius[1] << 16));
            dhi[2] = (int)(hius[2] | (hius[3] << 16)); dhi[3] = (int)(hius[4] | (hius[5] << 16));
            dlo[0] = tau + 1; dlo[1] = (int)(lous[0] | (lous[1] << 16));
            dlo[2] = (int)(lous[2] | (lous[3] << 16)); dlo[3] = (int)(lous[4] | (lous[5] << 16));
            i32x4* pb = hb_st + ((size_t)(dir * 2 + (par ^ 1)) * 64 + b0 + b) * 100 + g * 10 + c5;
            // guard against same-address store reorder with publish from 2 steps ago
            asm volatile("s_waitcnt vmcnt(0)" ::: "memory");
            asm volatile("global_store_dwordx4 %0, %1, off sc0 sc1" :: "v"(pb), "v"(dhi) : "memory");
            asm volatile("global_store_dwordx4 %0, %1, off sc0 sc1" :: "v"(pb + 5), "v"(dlo) : "memory");
            float* op = out + ((size_t)(b0 + b) * S_LEN + s) * 600 + dir * 300 + g * 30 + jj0;
#pragma unroll
            for (int u = 0; u < 6; ++u) op[u] = hv[u];
        }

        // 5) X(t+1) prefetch (overlaps teammates' publish transit)
        if (tau < S_LEN - 1) {
            const int sn = dir ? (s - 1) : (s + 1);
            const __hip_bfloat16* xp = X + (((size_t)dir * 512 + sn) * 64 + b0) * 1280 + g * 128;
#pragma unroll
            for (int r = 0; r < 4; ++r) {
                int m = hi4 * 4 + r;
                xa[r]     = xp[(size_t)m * 1280 + n0 + bb];
                xa[4 + r] = xp[(size_t)m * 1280 + n0 + 16 + bb];
            }
        }
        // no end barrier: next step's poll is the synchronization
    }
}

// ---------------------------------------------------------------------------
extern "C" void kernel_launch(void* const* d_in, const int* in_sizes, int n_in,
                              void* d_out, int out_size, void* d_ws, size_t ws_size,
                              hipStream_t stream) {
    const int*   cf    = (const int*)d_in[0];
    const int*   bl    = (const int*)d_in[1];
    const int*   br    = (const int*)d_in[2];
    const int*   scf   = (const int*)d_in[3];
    const int*   sbl   = (const int*)d_in[4];
    const int*   sbr   = (const int*)d_in[5];
    const float* ce    = (const float*)d_in[6];
    const float* be    = (const float*)d_in[7];
    const float* sce   = (const float*)d_in[8];
    const float* sbe   = (const float*)d_in[9];
    const float* Wlin  = (const float*)d_in[10];
    const float* blin  = (const float*)d_in[11];
    const float* Wih_l = (const float*)d_in[12];
    const float* Whh_l = (const float*)d_in[13];
    const float* b_l   = (const float*)d_in[14];
    const float* Wih_r = (const float*)d_in[15];
    const float* Whh_r = (const float*)d_in[16];
    const float* b_r   = (const float*)d_in[17];
    float* out = (float*)d_out;

    // Workspace layout (bytes):
    //   A bf16   [2][32768][320]     :  41,943,040
    //   X bf16   [2][512][64][1280]  : 167,772,160  (ends 209,715,200)
    //   Whh_p bf16 [2][1280][320]    :   1,638,400  (ends 211,353,600)
    //   Wih_p bf16 [2][1280][320]    :   1,638,400  (ends 212,992,000)
    //   bias_p f32 [2][1280]         :      10,240  (ends 213,002,240)
    //   hb_st  i32x4 [2][2][64][100] :     409,600  (ends 213,411,840)
    char* ws = (char*)d_ws;
    __hip_bfloat16* A_b    = (__hip_bfloat16*)(ws);
    __hip_bfloat16* A_l    = A_b;
    __hip_bfloat16* A_r    = A_b + (size_t)32768 * 320;
    __hip_bfloat16* X      = (__hip_bfloat16*)(ws + 41943040);
    __hip_bfloat16* Whh_p  = (__hip_bfloat16*)(ws + 209715200);
    __hip_bfloat16* Wih_p  = (__hip_bfloat16*)(ws + 211353600);
    float*          bias_p = (float*)(ws + 212992000);
    i32x4*          hb_st  = (i32x4*)(ws + 213002240);

    k_prep_w<<<dim3((2 * 1280 * 320 + 255) / 256), dim3(256), 0, stream>>>(
        Whh_l, Whh_r, Wih_l, Wih_r, Whh_p, Wih_p);
    k_prep_misc<<<dim3(1280), dim3(256), 0, stream>>>(b_l, b_r, (int*)hb_st, bias_p);
    k_lin<<<dim3(512, 2), dim3(256), 0, stream>>>(cf, bl, br, scf, sbl, sbr,
                                                  ce, be, sce, sbe, Wlin, blin,
                                                  A_l, A_r);
    k_xgemm<<<dim3(512, 10, 2), dim3(256), 0, stream>>>(A_b, Wih_p, bias_p, X);
    k_rec<<<dim3(80), dim3(256), 0, stream>>>(X, Whh_p, hb_st, out);
}